// Round 9
// baseline (302.025 us; speedup 1.0000x reference)
//
#include <hip/hip_runtime.h>

#define BS   8192
#define DIM  1024
#define TINV 10.0f    // 1 / TEMPERATURE
#define MARGIN 1.0f   // max(0.01, 1.0 - 0.1*0.0)

#define BM  128
#define BN  64
#define BKB 128       // fp8 K-bytes per tile (16x16x128 MFMA)
#define NT  (DIM / BKB)   // 8 K-tiles

// fp8 values are the normalized elements scaled by 16 -> dot = 256 * cos
#define QSCALE   16.0f
#define INV_QSQ  (1.0f / 256.0f)

typedef __attribute__((ext_vector_type(4))) float f32x4;
typedef __attribute__((ext_vector_type(4))) int   int4v;
typedef __attribute__((ext_vector_type(8))) int   int8v;

// ---------------- Kernel 1: L2-normalize rows, emit fp8(e4m3,x16) + posdist -
// (unchanged — one wave per row, pure shfl reduction)
__global__ __launch_bounds__(256) void normalize_kernel(
    const float* __restrict__ feat,
    unsigned char* __restrict__ Afp8,
    unsigned char* __restrict__ Nfp8,
    float* __restrict__ posdist)
{
    const int lane = threadIdx.x & 63;
    const int row  = blockIdx.x * 4 + (threadIdx.x >> 6);   // wave = row

    const float4* fo = (const float4*)(feat + (size_t)row * DIM);
    const float4* fp = (const float4*)(feat + (size_t)(BS + row) * DIM);
    const float4* fn = (const float4*)(feat + (size_t)(2 * BS + row) * DIM);

    float4 o[4], p[4], n[4];
    #pragma unroll
    for (int k = 0; k < 4; k++) {
        o[k] = fo[lane + 64 * k];
        p[k] = fp[lane + 64 * k];
        n[k] = fn[lane + 64 * k];
    }

    float so = 0.f, sp = 0.f, sn = 0.f;
    #pragma unroll
    for (int k = 0; k < 4; k++) {
        so += o[k].x*o[k].x + o[k].y*o[k].y + o[k].z*o[k].z + o[k].w*o[k].w;
        sp += p[k].x*p[k].x + p[k].y*p[k].y + p[k].z*p[k].z + p[k].w*p[k].w;
        sn += n[k].x*n[k].x + n[k].y*n[k].y + n[k].z*n[k].z + n[k].w*n[k].w;
    }
    #pragma unroll
    for (int off = 1; off < 64; off <<= 1) {
        so += __shfl_xor(so, off);
        sp += __shfl_xor(sp, off);
        sn += __shfl_xor(sn, off);
    }

    const float io  = 1.0f / fmaxf(sqrtf(so), 1e-12f);
    const float ip  = 1.0f / fmaxf(sqrtf(sp), 1e-12f);
    const float in_ = 1.0f / fmaxf(sqrtf(sn), 1e-12f);

    int* Ar = (int*)(Afp8 + (size_t)row * DIM);
    int* Nr = (int*)(Nfp8 + (size_t)row * DIM);

    float d = 0.f;
    #pragma unroll
    for (int k = 0; k < 4; k++) {
        float ax = o[k].x*io, ay = o[k].y*io, az = o[k].z*io, aw = o[k].w*io;
        float nx = n[k].x*in_, ny = n[k].y*in_, nz = n[k].z*in_, nw = n[k].w*in_;
        int pa = __builtin_amdgcn_cvt_pk_fp8_f32(ax*QSCALE, ay*QSCALE, 0, false);
        pa     = __builtin_amdgcn_cvt_pk_fp8_f32(az*QSCALE, aw*QSCALE, pa, true);
        int pn = __builtin_amdgcn_cvt_pk_fp8_f32(nx*QSCALE, ny*QSCALE, 0, false);
        pn     = __builtin_amdgcn_cvt_pk_fp8_f32(nz*QSCALE, nw*QSCALE, pn, true);
        Ar[lane + 64 * k] = pa;      // coalesced 4B stores
        Nr[lane + 64 * k] = pn;
        float dx = ax - p[k].x*ip, dy = ay - p[k].y*ip;
        float dz = az - p[k].z*ip, dw = aw - p[k].w*ip;
        d += dx*dx + dy*dy + dz*dz + dw*dw;
    }
    #pragma unroll
    for (int off = 1; off < 64; off <<= 1) d += __shfl_xor(d, off);
    if (lane == 0) posdist[row] = d * TINV;
}

// Load one 32B fragment from swizzled LDS: lo chunk at `off`, hi at off^16
// (chunk parity: (q2+1)^x == (q2^x)^1 for even q2). Union avoids repack.
__device__ __forceinline__ int8v ld_frag(const unsigned char* __restrict__ p,
                                         int off) {
    union { int8v v; struct { int4v lo, hi; } s; } u;
    u.s.lo = *(const int4v*)(p + off);
    u.s.hi = *(const int4v*)(p + (off ^ 16));
    return u.v;
}

// Load one 32B A-fragment straight from global (contiguous, no swizzle).
__device__ __forceinline__ int8v ld_glob(const unsigned char* __restrict__ p) {
    union { int8v v; struct { int4v lo, hi; } s; } u;
    u.s.lo = *(const int4v*)(p);
    u.s.hi = *(const int4v*)(p + 16);
    return u.v;
}

// ---------------- Kernel 2: MX-fp8 16x16x128 MFMA max-GEMM (R19) ------------
// R19 = "R16 done right": B-only LDS (A never shared: each A-frag is read
// by exactly ONE wave, so its LDS staging was pure pass-through), with A
// prefetched into NAMED register sets TWO tiles ahead (T14 async-split) so
// L2 latency (~200cyc) hides under ~2 full compute iterations. R16 failed
// only because A was issued+consumed in the same iteration (MfmaUtil 18%).
// Evidence base: R9/R12/R18 — three schedules, identical 110 us, MfmaUtil
// 26% -> hard-resource-bound, and the only ~saturated pipe is LDS data
// return (12288 b128/CU x ~16cyc ~= 197K of 264K cyc). This cuts LDS reads
// 12 -> 8 per wave-iter (-33%), LDS 24 -> 16 KB (B dbuf only).
// vmcnt ledger (6 vm-ops/body: 2 B gload_lds + 4 A dwordx4):
//   prologue: B0,A0,B1,A1 (12 in flight) -> vmcnt(6) retires tile0 -> bar.
//   body t: compute(t) -> bar -> stage B(t+2)+load A(t+2) -> vmcnt(6)
//           retires tile t+1's 6 (t+2's ride across) -> bar.
//   bodies 6,7 peeled: no staging; vmcnt(0) before body 7.
// Rule #20: A-sets are named aA0/aA1/aB0/aB1, loop 2x-unrolled, no runtime
// indexing. No launch_bounds forcing (R15 spill lesson).
__global__ __launch_bounds__(256) void maxgemm_kernel(
    const unsigned char* __restrict__ Afp8,
    const unsigned char* __restrict__ Nfp8,
    float* __restrict__ partial)   // [128][BS]: stripe-major (transposed)
{
    __shared__ unsigned char Bs[2][BN * BKB];   // 2 x 8 KiB — B only

    const int tid  = threadIdx.x;
    const int lane = tid & 63;
    const int w    = tid >> 6;
    const int rowBase = blockIdx.y * BM;
    const int colBase = blockIdx.x * BN;

    const int lrow = lane >> 3;                      // 0..7: row in 8-row slab
    const int gcol = ((lane & 7) ^ lrow) * 16;       // swizzled 16B chunk (bytes)

    const unsigned char* Bg = Nfp8 + (size_t)colBase * DIM;

    // A: per-lane global base (validated in R16, absmax=0). Lane reads row
    // (lane&15) of its wave's 32-row strip, 32B K-segment (lane>>4)*32;
    // frag i=1 at +16 rows.
    const unsigned char* Ap =
        Afp8 + (size_t)(rowBase + w * 32 + (lane & 15)) * DIM + ((lane >> 4) * 32);

    const int q2   = (lane >> 4) * 2;                // first 16B chunk of quad
    const int brow = (lane & 15);                    // + j*16, j=0..3
    const int boff = brow * BKB + ((q2 ^ (brow & 7)) << 4);

    f32x4 acc[2][4];
    #pragma unroll
    for (int i = 0; i < 2; i++)
        #pragma unroll
        for (int j = 0; j < 4; j++)
            acc[i][j] = (f32x4){0.f, 0.f, 0.f, 0.f};

#define STAGE_B(BUF, T)                                                       \
    {                                                                         \
        const int k0_ = (T) * BKB;                                            \
        _Pragma("unroll")                                                     \
        for (int s = 0; s < 2; s++) {                                         \
            const int r0 = (w * 2 + s) * 8;                                   \
            __builtin_amdgcn_global_load_lds(                                 \
                (const __attribute__((address_space(1))) void*)               \
                    (Bg + (size_t)(r0 + lrow) * DIM + k0_ + gcol),            \
                (__attribute__((address_space(3))) void*)(Bs[BUF] + r0 * BKB),\
                16, 0, 0);                                                    \
        }                                                                     \
    }

#define LOAD_A(T, A0, A1)                                                     \
    {                                                                         \
        A0 = ld_glob(Ap + (T) * BKB);                                         \
        A1 = ld_glob(Ap + (T) * BKB + 16 * DIM);                              \
    }

#define COMPUTE(BUF, A0, A1)                                                  \
    {                                                                         \
        int8v bf[4];                                                          \
        _Pragma("unroll")                                                     \
        for (int j = 0; j < 4; j++)                                           \
            bf[j] = ld_frag(Bs[BUF], boff + j * 16 * BKB);                    \
        _Pragma("unroll")                                                     \
        for (int j = 0; j < 4; j++) {                                         \
            acc[0][j] = __builtin_amdgcn_mfma_scale_f32_16x16x128_f8f6f4(     \
                A0, bf[j], acc[0][j], 0, 0, 0, 0x7F7F7F7F, 0, 0x7F7F7F7F);    \
            acc[1][j] = __builtin_amdgcn_mfma_scale_f32_16x16x128_f8f6f4(     \
                A1, bf[j], acc[1][j], 0, 0, 0, 0x7F7F7F7F, 0, 0x7F7F7F7F);    \
        }                                                                     \
    }

#define FENCE asm volatile("" ::: "memory")

    int8v aA0, aA1, aB0, aB1;

    // ---- prologue: tiles 0,1 fully in flight (12 vm-ops) ----
    STAGE_B(0, 0);
    LOAD_A(0, aA0, aA1);
    STAGE_B(1, 1);
    LOAD_A(1, aB0, aB1);
    asm volatile("s_waitcnt vmcnt(6)" ::: "memory");  // tile0 B+A landed (mine)
    __builtin_amdgcn_s_barrier();                     // everyone's tile0 B in LDS
    FENCE;

    for (int t = 0; t < 6; t += 2) {
        // ---- body t (even): buf0 / set A ----
        COMPUTE(0, aA0, aA1);
        FENCE;
        __builtin_amdgcn_s_barrier();   // all waves done reading Bs[0]
        FENCE;
        STAGE_B(0, t + 2);
        LOAD_A(t + 2, aA0, aA1);
        asm volatile("s_waitcnt vmcnt(6)" ::: "memory");  // tile t+1 landed
        __builtin_amdgcn_s_barrier();
        FENCE;

        // ---- body t+1 (odd): buf1 / set B ----
        COMPUTE(1, aB0, aB1);
        FENCE;
        __builtin_amdgcn_s_barrier();   // all waves done reading Bs[1]
        FENCE;
        STAGE_B(1, t + 3);
        LOAD_A(t + 3, aB0, aB1);
        asm volatile("s_waitcnt vmcnt(6)" ::: "memory");  // tile t+2 landed
        __builtin_amdgcn_s_barrier();
        FENCE;
    }
    // ---- body 6 (buf0/setA): nothing left to stage ----
    COMPUTE(0, aA0, aA1);
    FENCE;
    asm volatile("s_waitcnt vmcnt(0)" ::: "memory");  // tile7 drained (mine)
    __builtin_amdgcn_s_barrier();                     // everyone's tile7 in LDS
    FENCE;
    // ---- body 7 (buf1/setB) ----
    COMPUTE(1, aB0, aB1);

#undef STAGE_B
#undef LOAD_A
#undef COMPUTE
#undef FENCE

    // Epilogue: per-row max over this block's 64 columns (all in this wave).
    // C/D layout (m89/m91): col = lane&15, row = (lane>>4)*4 + reg.
    // Transposed store: wave w's 32 rows fully dirty one 128B line.
    const int stripe = blockIdx.x;
    #pragma unroll
    for (int i = 0; i < 2; i++) {
        #pragma unroll
        for (int r = 0; r < 4; r++) {
            float v = fmaxf(fmaxf(acc[i][0][r], acc[i][1][r]),
                            fmaxf(acc[i][2][r], acc[i][3][r]));
            v = fmaxf(v, __shfl_xor(v, 1));
            v = fmaxf(v, __shfl_xor(v, 2));
            v = fmaxf(v, __shfl_xor(v, 4));
            v = fmaxf(v, __shfl_xor(v, 8));
            if ((lane & 15) == 0) {
                const int row = rowBase + w * 32 + i * 16 + (lane >> 4) * 4 + r;
                partial[(size_t)stripe * BS + row] = v;   // = 256 * cos
            }
        }
    }
}

// ---------------- Kernel 3: stripe-max -> loss terms -> per-block partials --
// [stripe][row] layout: one thread per row; 128 coalesced stripe-loads.
__global__ __launch_bounds__(256) void reduce_kernel(
    const float* __restrict__ partial,   // [128][BS]
    const float* __restrict__ posdist,
    float* __restrict__ blockpart)       // [32][3]
{
    const int tid = threadIdx.x;
    const int gid = blockIdx.x * 256 + tid;   // row this thread owns

    float m = -1e30f;
    #pragma unroll 8
    for (int s = 0; s < 128; s++)
        m = fmaxf(m, partial[(size_t)s * BS + gid]);

    // m = 256*cos  ->  hard = (2 - 2*cos)/T = (2 - m/128)*TINV
    const float hard = (2.0f - 2.0f * m * INV_QSQ) * TINV;
    const float pos  = posdist[gid];
    float sloss = fmaxf(MARGIN + pos - hard, 0.0f);
    float spos  = pos;
    float shard = hard;

    #pragma unroll
    for (int off = 1; off < 64; off <<= 1) {
        sloss += __shfl_xor(sloss, off);
        spos  += __shfl_xor(spos,  off);
        shard += __shfl_xor(shard, off);
    }

    __shared__ float red[4][3];
    const int lane = tid & 63, w = tid >> 6;
    if (lane == 0) { red[w][0] = sloss; red[w][1] = spos; red[w][2] = shard; }
    __syncthreads();
    if (tid == 0) {
        #pragma unroll
        for (int k = 0; k < 3; k++)
            blockpart[blockIdx.x * 3 + k] =
                red[0][k] + red[1][k] + red[2][k] + red[3][k];
    }
}

// ---------------- Kernel 4: finalize means (one wave, no atomics) -----------
__global__ __launch_bounds__(64) void finalize_kernel(
    const float* __restrict__ blockpart,   // [32][3]
    float* __restrict__ out)
{
    const int lane = threadIdx.x;
    float a = 0.f, b = 0.f, c = 0.f;
    if (lane < 32) {
        a = blockpart[lane * 3 + 0];
        b = blockpart[lane * 3 + 1];
        c = blockpart[lane * 3 + 2];
    }
    #pragma unroll
    for (int off = 1; off < 64; off <<= 1) {
        a += __shfl_xor(a, off);
        b += __shfl_xor(b, off);
        c += __shfl_xor(c, off);
    }
    if (lane == 0) {
        const float inv = 1.0f / (float)BS;
        out[0] = a * inv;
        out[1] = b * inv;
        out[2] = c * inv;
    }
}

extern "C" void kernel_launch(void* const* d_in, const int* in_sizes, int n_in,
                              void* d_out, int out_size, void* d_ws, size_t ws_size,
                              hipStream_t stream) {
    const float* feat = (const float*)d_in[0];
    char* ws = (char*)d_ws;

    // ws layout: Afp8 8MiB | Nfp8 8MiB | partial 4MiB | posdist 32KiB | blockpart
    unsigned char* Afp8      = (unsigned char*)ws;
    unsigned char* Nfp8      = (unsigned char*)(ws + ((size_t)8 << 20));
    float*         partial   = (float*)(ws + ((size_t)16 << 20));
    float*         posdist   = (float*)(ws + ((size_t)20 << 20));
    float*         blockpart = (float*)(ws + ((size_t)20 << 20) + 32768);

    normalize_kernel<<<BS / 4, 256, 0, stream>>>(feat, Afp8, Nfp8, posdist);

    maxgemm_kernel<<<dim3(BS / BN, BS / BM), 256, 0, stream>>>(Afp8, Nfp8, partial);

    reduce_kernel<<<BS / 256, 256, 0, stream>>>(partial, posdist, blockpart);
    finalize_kernel<<<1, 64, 0, stream>>>(blockpart, (float*)d_out);
}